// Round 14
// baseline (2097.034 us; speedup 1.0000x reference)
//
#include <hip/hip_runtime.h>

#define D_IN 8
#define D_MODEL 1024
#define DEPTH 12
#define D_INNER 2048
#define D_STATE 16
#define D_CONV 4
#define DT_RANK 64
#define BATCH 512

typedef unsigned short ushort_t;
typedef unsigned int uint_t;
typedef __attribute__((ext_vector_type(8))) short short8;
typedef __attribute__((ext_vector_type(16))) float f32x16;

#if defined(__has_builtin)
#if __has_builtin(__builtin_amdgcn_global_load_lds)
#define USE_GLL 1
#endif
#endif

__device__ __forceinline__ float sigmoidf_(float x) { return 1.f / (1.f + expf(-x)); }
__device__ __forceinline__ float siluf_(float x) { return x * sigmoidf_(x); }
__device__ __forceinline__ float softplusf_(float x) { return fmaxf(x, 0.f) + log1pf(expf(-fabsf(x))); }

__device__ __forceinline__ float waveRedSum(float v) {
#pragma unroll
  for (int off = 32; off; off >>= 1) v += __shfl_xor(v, off);
  return v;
}

// ---- bf16 3-way split helpers (RNE) ----
__device__ __forceinline__ ushort_t f2bf(float x) {
  uint_t u = __float_as_uint(x);
  u += 0x7fffu + ((u >> 16) & 1u);
  return (ushort_t)(u >> 16);
}
__device__ __forceinline__ float bf2f(ushort_t h) { return __uint_as_float((uint_t)h << 16); }
__device__ __forceinline__ void split3(float x, ushort_t& s0, ushort_t& s1, ushort_t& s2) {
  s0 = f2bf(x); float r = x - bf2f(s0);
  s1 = f2bf(r); r -= bf2f(s1);
  s2 = f2bf(r);
}
__device__ __forceinline__ uint4 pack8(const ushort_t* u) {
  uint4 v;
  v.x = (uint_t)u[0] | ((uint_t)u[1] << 16);
  v.y = (uint_t)u[2] | ((uint_t)u[3] << 16);
  v.z = (uint_t)u[4] | ((uint_t)u[5] << 16);
  v.w = (uint_t)u[6] | ((uint_t)u[7] << 16);
  return v;
}

// A-tile geometry (LDS): 32-ushort (64B) rows, 4x16B slots, slot' = slot^((row>>1)&3).
__device__ __forceinline__ int slotx(int row, int slot) { return slot ^ ((row >> 1) & 3); }

// staging: copy 16B per lane; GLL path: lds base wave-uniform, HW adds lane*16.
__device__ __forceinline__ void stage16(const ushort_t* gbase, ushort_t* lbase, int lane) {
#ifdef USE_GLL
  __builtin_amdgcn_global_load_lds(
      (const __attribute__((address_space(1))) unsigned int*)(gbase + lane * 8),
      (__attribute__((address_space(3))) unsigned int*)lbase, 16, 0, 0);
#else
  *(uint4*)(lbase + lane * 8) = *(const uint4*)(gbase + lane * 8);
#endif
}

// ---- weight pre-split into FRAGMENT-ORDERED B layout ----
// chunk(nb, kt, ks, wm, nf, s)[lane][8] ; lane = hi*32 + lo where
// n = nb*128 + wm*64 + nf*32 + lo ; k = kt*32 + (ks*2+hi)*8 + [0..8)
// per-(nb,kt) stride = 24 chunks * 512 = 12288 ushorts (same as before).
__global__ __launch_bounds__(256) void k_presplit(const float* __restrict__ W,
    ushort_t* __restrict__ Bt, int K, int items) {
  const int KB = K >> 5;
  const int kpr = K >> 3;
  for (int i = blockIdx.x * 256 + threadIdx.x; i < items; i += gridDim.x * 256) {
    const int n = i / kpr, k0 = (i - n * kpr) * 8;
    const float* g = W + (size_t)n * K + k0;
    float fv[8];
    *(float4*)&fv[0] = *(const float4*)(g + 0);
    *(float4*)&fv[4] = *(const float4*)(g + 4);
    ushort_t u0[8], u1[8], u2[8];
#pragma unroll
    for (int j = 0; j < 8; ++j) split3(fv[j], u0[j], u1[j], u2[j]);
    const int nb = n >> 7, wm = (n >> 6) & 1, nf = (n >> 5) & 1, lo = n & 31;
    const int kt = k0 >> 5, sl = (k0 >> 3) & 3, ks = sl >> 1, hi = sl & 1;
    const int lane = hi * 32 + lo;
    const size_t dst = (size_t)(nb * KB + kt) * 12288
                       + (size_t)(((ks * 2 + wm) * 2 + nf) * 3) * 512 + lane * 8;
    *(uint4*)&Bt[dst]        = pack8(u0);
    *(uint4*)&Bt[dst + 512]  = pack8(u1);
    *(uint4*)&Bt[dst + 1024] = pack8(u2);
  }
}

// negA = -exp(A_log), all layers (12*2048*16 floats)
__global__ __launch_bounds__(256) void k_negA(const float* __restrict__ alog,
    float* __restrict__ negA, int items) {
  int i = blockIdx.x * 256 + threadIdx.x;
  if (i < items) negA[i] = -expf(alog[i]);
}

// h[b,m] -> tiled A-layout h_t: [mb][kb(32)][3][64 rows][32]
__global__ __launch_bounds__(256) void k_input_proj(const float* __restrict__ xt,
    const float* __restrict__ Win, const float* __restrict__ bin,
    ushort_t* __restrict__ h_t) {
  int idx = blockIdx.x * 256 + threadIdx.x;
  int b = idx >> 10, m = idx & 1023;
  float acc = bin[m];
  const float* xr = xt + b * D_IN;
  const float* wr = Win + m * D_IN;
#pragma unroll
  for (int k = 0; k < D_IN; ++k) acc += xr[k] * wr[k];
  ushort_t s0, s1, s2; split3(acc, s0, s1, s2);
  const int mb = b >> 6, r = b & 63, kb = m >> 5;
  const int so = slotx(r, (m >> 3) & 3) * 8;
  const size_t base = ((size_t)(mb * 32 + kb) * 3) * 2048 + r * 32 + so + (m & 7);
  h_t[base] = s0; h_t[base + 2048] = s1; h_t[base + 4096] = s2;
}

// P_partial[kb] = A . B^T. Block 64m x 128n, BK=32, 4 waves (2 n-groups x 2 k-chunks).
// A staged via GLL into LDS (shared x2); B loaded fragment-direct from global
// (zero cross-wave sharing -> no LDS round-trip; 6 coalesced 1KB b128/wave/step).
template <int MBLK, int NBLK, int KSPLIT, int KB>
__global__ __launch_bounds__(256, 4) void k_gemm6(
    const ushort_t* __restrict__ At, const ushort_t* __restrict__ Bt,
    float* __restrict__ P, int N) {
  __shared__ __align__(16) ushort_t lds[18432];  // 36864 B (A stage 12KB + reduce scratch)
  const int t = threadIdx.x, lane = t & 63, w = t >> 6;
  const int wm = w >> 1;   // n-group (0,1)
  const int ks = w & 1;    // k16-chunk (0,1)

  constexpr int GRID = MBLK * NBLK * KSPLIT;
  constexpr int STEPS = KB / KSPLIT;
  const int id = blockIdx.x;
  const int swz = (id & 7) * (GRID >> 3) + (id >> 3);
  const int kb = swz / (MBLK * NBLK);
  const int r2 = swz % (MBLK * NBLK);
  const int mb = r2 % MBLK, nb = r2 / MBLK;

  f32x16 acc[2][2];
#pragma unroll
  for (int i = 0; i < 2; ++i)
#pragma unroll
    for (int j = 0; j < 2; ++j)
#pragma unroll
      for (int r = 0; r < 16; ++r) acc[i][j][r] = 0.f;

  const size_t bfrag_off = (size_t)(((ks * 2 + wm) * 2) * 3) * 512 + lane * 8;

  for (int step = 0; step < STEPS; ++step) {
    const int kt = kb * STEPS + step;
    const ushort_t* gA = At + ((size_t)(mb * KB + kt)) * 6144;
    const ushort_t* gB = Bt + ((size_t)(nb * KB + kt)) * 12288 + bfrag_off;

    // B fragments: straight to registers (no barrier dependency)
    short8 bf[2][3];
#pragma unroll
    for (int nf = 0; nf < 2; ++nf)
#pragma unroll
      for (int s = 0; s < 3; ++s)
        bf[nf][s] = *(const short8*)(gB + (nf * 3 + s) * 512);

    __syncthreads();
#pragma unroll
    for (int i = 0; i < 3; ++i) {
      const int c = w + i * 4;  // 0..11 (A chunks only)
      stage16(gA + c * 512, &lds[c * 512], lane);
    }
    __syncthreads();

    const int kslot = ks * 2 + (lane >> 5);
    short8 af[2][3];
#pragma unroll
    for (int mf = 0; mf < 2; ++mf) {
      const int r = mf * 32 + (lane & 31);
      const int so = slotx(r, kslot) * 8;
#pragma unroll
      for (int s = 0; s < 3; ++s)
        af[mf][s] = *(const short8*)&lds[s * 2048 + r * 32 + so];
    }
#pragma unroll
    for (int mf = 0; mf < 2; ++mf)
#pragma unroll
      for (int nf = 0; nf < 2; ++nf) {
        acc[mf][nf] = __builtin_amdgcn_mfma_f32_32x32x16_bf16(af[mf][0], bf[nf][0], acc[mf][nf], 0, 0, 0);
        acc[mf][nf] = __builtin_amdgcn_mfma_f32_32x32x16_bf16(af[mf][0], bf[nf][1], acc[mf][nf], 0, 0, 0);
        acc[mf][nf] = __builtin_amdgcn_mfma_f32_32x32x16_bf16(af[mf][1], bf[nf][0], acc[mf][nf], 0, 0, 0);
        acc[mf][nf] = __builtin_amdgcn_mfma_f32_32x32x16_bf16(af[mf][1], bf[nf][1], acc[mf][nf], 0, 0, 0);
        acc[mf][nf] = __builtin_amdgcn_mfma_f32_32x32x16_bf16(af[mf][2], bf[nf][0], acc[mf][nf], 0, 0, 0);
        acc[mf][nf] = __builtin_amdgcn_mfma_f32_32x32x16_bf16(af[mf][0], bf[nf][2], acc[mf][nf], 0, 0, 0);
      }
  }

  // in-block reduce of 2 k-chunks (ks=1 -> ks=0), write partial tile
  __syncthreads();
  float* red = (float*)lds;
  const int rbase = (wm * 64 + lane) * 68;  // 34816 B <= 36864
  if (ks == 1) {
#pragma unroll
    for (int j = 0; j < 16; ++j) {
      const int mf = j >> 3, nf = (j >> 2) & 1, r0 = (j & 3) * 4;
      float4 v;
      v.x = acc[mf][nf][r0 + 0]; v.y = acc[mf][nf][r0 + 1];
      v.z = acc[mf][nf][r0 + 2]; v.w = acc[mf][nf][r0 + 3];
      *(float4*)&red[rbase + j * 4] = v;
    }
  }
  __syncthreads();
  if (ks == 0) {
#pragma unroll
    for (int j = 0; j < 16; ++j) {
      const int mf = j >> 3, nf = (j >> 2) & 1, r0 = (j & 3) * 4;
      float4 v = *(const float4*)&red[rbase + j * 4];
      acc[mf][nf][r0 + 0] += v.x; acc[mf][nf][r0 + 1] += v.y;
      acc[mf][nf][r0 + 2] += v.z; acc[mf][nf][r0 + 3] += v.w;
    }
    float* Pk = P + (size_t)kb * 512 * N;
    const int n0 = nb * 128, m0 = mb * 64;
#pragma unroll
    for (int mf = 0; mf < 2; ++mf) {
      const int n = n0 + wm * 64 + (lane & 31);
#pragma unroll
      for (int nf = 0; nf < 2; ++nf)
#pragma unroll
        for (int r = 0; r < 16; ++r) {
          const int m = m0 + mf * 32 + (r & 3) + 8 * (r >> 2) + 4 * (lane >> 5);
          Pk[(size_t)m * N + n + nf * 32] = acc[mf][nf][r];
        }
    }
  }
}

// Fused: (sum 4 Pin partials) conv+SiLU -> x_proj (vectorized) -> dt_proj+softplus
// -> SSM (vectorized sst/negA) -> gate. 1 batch row per block, 512 blocks. (r11)
__global__ __launch_bounds__(256) void k_fused(
    const float* __restrict__ Pin,   // [4][512][4096]
    const float* __restrict__ cst, const float* __restrict__ sst,
    const float* __restrict__ cw, const float* __restrict__ cb,
    const float* __restrict__ xpw, const float* __restrict__ dtw, const float* __restrict__ dtb,
    const float* __restrict__ negA, const float* __restrict__ dpar,
    ushort_t* __restrict__ y_t) {
  __shared__ float sxc[D_INNER];
  __shared__ float sxdb[96];
  const int t = threadIdx.x;
  const int b = blockIdx.x;
  const size_t S = 2097152;

  for (int d = t; d < D_INNER; d += 256) {
    float4 c = *(const float4*)&cst[((size_t)b * D_INNER + d) * 4];
    float4 w = *(const float4*)&cw[d * 4];
    const size_t xi = (size_t)b * 4096 + d;
    float xv = Pin[xi] + Pin[xi + S] + Pin[xi + 2 * S] + Pin[xi + 3 * S];
    float a = c.y * w.x + c.z * w.y + c.w * w.z + xv * w.w + cb[d];
    sxc[d] = siluf_(a);
  }
  __syncthreads();

  const int wave = t >> 6, lane = t & 63;
  const int lane4 = lane * 4;
  for (int r0 = wave * 24; r0 < wave * 24 + 24; r0 += 2) {
    const float* w0 = &xpw[(size_t)r0 * D_INNER];
    const float* w1 = w0 + D_INNER;
    float a0 = 0.f, a1 = 0.f, c0 = 0.f, c1 = 0.f;
#pragma unroll
    for (int it = 0; it < 8; ++it) {
      const int k = it * 256 + lane4;
      float4 x  = *(const float4*)&sxc[k];
      float4 wa = *(const float4*)&w0[k];
      float4 wb = *(const float4*)&w1[k];
      a0 += wa.x * x.x + wa.y * x.y;  a1 += wa.z * x.z + wa.w * x.w;
      c0 += wb.x * x.x + wb.y * x.y;  c1 += wb.z * x.z + wb.w * x.w;
    }
    float ra = waveRedSum(a0 + a1);
    float rb = waveRedSum(c0 + c1);
    if (lane == 0) { sxdb[r0] = ra; sxdb[r0 + 1] = rb; }
  }
  __syncthreads();

  for (int d = t; d < D_INNER; d += 256) {
    float dtr = dtb[d];
#pragma unroll
    for (int j4 = 0; j4 < DT_RANK / 4; ++j4) {
      float4 wv = *(const float4*)&dtw[(size_t)d * DT_RANK + j4 * 4];
      dtr += sxdb[j4 * 4] * wv.x + sxdb[j4 * 4 + 1] * wv.y +
             sxdb[j4 * 4 + 2] * wv.z + sxdb[j4 * 4 + 3] * wv.w;
    }
    float dtv = softplusf_(dtr);
    float xcv = sxc[d];
    float dx = dtv * xcv;
    const float4* srow4 = (const float4*)&sst[((size_t)b * D_INNER + d) * D_STATE];
    const float4* na4 = (const float4*)&negA[(size_t)d * D_STATE];
    float acc = 0.f;
#pragma unroll
    for (int q = 0; q < 4; ++q) {
      float4 sv = srow4[q];
      float4 na = na4[q];
      float4 Bn = *(const float4*)&sxdb[DT_RANK + q * 4];
      float4 Cn = *(const float4*)&sxdb[DT_RANK + D_STATE + q * 4];
      acc += (sv.x * expf(dtv * na.x) + dx * Bn.x) * Cn.x;
      acc += (sv.y * expf(dtv * na.y) + dx * Bn.y) * Cn.y;
      acc += (sv.z * expf(dtv * na.z) + dx * Bn.z) * Cn.z;
      acc += (sv.w * expf(dtv * na.w) + dx * Bn.w) * Cn.w;
    }
    float yv = acc + dpar[d] * xcv;
    const size_t zi = (size_t)b * 4096 + D_INNER + d;
    float zv = Pin[zi] + Pin[zi + S] + Pin[zi + 2 * S] + Pin[zi + 3 * S];
    yv *= siluf_(zv);
    ushort_t s0, s1, s2; split3(yv, s0, s1, s2);
    const int mb = b >> 6, r = b & 63, kb = d >> 5;
    const int so = slotx(r, (d >> 3) & 3) * 8;
    const size_t base = ((size_t)(mb * 64 + kb) * 3) * 2048 + r * 32 + so + (d & 7);
    y_t[base] = s0; y_t[base + 2048] = s1; y_t[base + 4096] = s2;
  }
}

// h = sum of 16 out_proj partials; emit h fp32 + tiled h splits (KB=32)
__global__ __launch_bounds__(256) void k_reduce_out(const float* __restrict__ P,
    float* __restrict__ h, ushort_t* __restrict__ h_t) {
  const int i = blockIdx.x * 256 + threadIdx.x;  // 131072 float4
  float4 a = ((const float4*)P)[i];
#pragma unroll
  for (int p = 1; p < 16; ++p) {
    float4 b = ((const float4*)P)[(size_t)p * 131072 + i];
    a.x += b.x; a.y += b.y; a.z += b.z; a.w += b.w;
  }
  ((float4*)h)[i] = a;
  float fv[4] = {a.x, a.y, a.z, a.w};
  ushort_t u0[4], u1[4], u2[4];
#pragma unroll
  for (int j = 0; j < 4; ++j) split3(fv[j], u0[j], u1[j], u2[j]);
  const int flat = i * 4;
  const int b = flat >> 10, k = flat & 1023;
  const int mb = b >> 6, r = b & 63, kb = k >> 5;
  const int so = slotx(r, (k >> 3) & 3) * 8;
  const size_t base = ((size_t)(mb * 32 + kb) * 3) * 2048 + r * 32 + so + (k & 7);
  *(uint2*)&h_t[base]        = make_uint2((uint_t)u0[0] | ((uint_t)u0[1] << 16), (uint_t)u0[2] | ((uint_t)u0[3] << 16));
  *(uint2*)&h_t[base + 2048] = make_uint2((uint_t)u1[0] | ((uint_t)u1[1] << 16), (uint_t)u1[2] | ((uint_t)u1[3] << 16));
  *(uint2*)&h_t[base + 4096] = make_uint2((uint_t)u2[0] | ((uint_t)u2[1] << 16), (uint_t)u2[2] | ((uint_t)u2[3] << 16));
}

__global__ __launch_bounds__(256) void k_layernorm(const float* __restrict__ h,
    const float* __restrict__ lnw, const float* __restrict__ lnb, float* __restrict__ out) {
  __shared__ float red[4];
  const int b = blockIdx.x, t = threadIdx.x;
  const float* row = h + (size_t)b * D_MODEL;
  float4 x = *(const float4*)&row[t * 4];
  float s = x.x + x.y + x.z + x.w;
  s = waveRedSum(s);
  const int wave = t >> 6, lane = t & 63;
  if (lane == 0) red[wave] = s;
  __syncthreads();
  float mu = (red[0] + red[1] + red[2] + red[3]) * (1.f / 1024.f);
  float d0 = x.x - mu, d1 = x.y - mu, d2 = x.z - mu, d3 = x.w - mu;
  float q = d0 * d0 + d1 * d1 + d2 * d2 + d3 * d3;
  q = waveRedSum(q);
  __syncthreads();
  if (lane == 0) red[wave] = q;
  __syncthreads();
  float var = (red[0] + red[1] + red[2] + red[3]) * (1.f / 1024.f);
  float inv = 1.f / sqrtf(var + 1e-5f);
  float4 wv = *(const float4*)&lnw[t * 4];
  float4 bv = *(const float4*)&lnb[t * 4];
  float4 o;
  o.x = d0 * inv * wv.x + bv.x;
  o.y = d1 * inv * wv.y + bv.y;
  o.z = d2 * inv * wv.z + bv.z;
  o.w = d3 * inv * wv.w + bv.w;
  *(float4*)&out[(size_t)b * D_MODEL + t * 4] = o;
}

extern "C" void kernel_launch(void* const* d_in, const int* in_sizes, int n_in,
                              void* d_out, int out_size, void* d_ws, size_t ws_size,
                              hipStream_t stream) {
  const float* x_t  = (const float*)d_in[0];
  const float* cst  = (const float*)d_in[1];
  const float* sst  = (const float*)d_in[2];
  const float* Win  = (const float*)d_in[3];
  const float* bin  = (const float*)d_in[4];
  const float* ipw  = (const float*)d_in[5];
  const float* cw   = (const float*)d_in[6];
  const float* cb   = (const float*)d_in[7];
  const float* xpw  = (const float*)d_in[8];
  const float* dtw  = (const float*)d_in[9];
  const float* dtb  = (const float*)d_in[10];
  const float* alog = (const float*)d_in[11];
  const float* dpar = (const float*)d_in[12];
  const float* opw  = (const float*)d_in[13];
  const float* lnw  = (const float*)d_in[14];
  const float* lnb  = (const float*)d_in[15];

  float* ws   = (float*)d_ws;
  float* h    = ws;                         // 524288 f32
  float* Pin  = h + 524288;                 // 4 x 2097152 f32
  float* Pout = Pin + 8388608;              // 16 x 524288 f32
  float* negA = Pout + 8388608;             // 393216 f32
  ushort_t* u = (ushort_t*)(negA + 393216);
  ushort_t* h_t = u;                        // 1572864
  ushort_t* y_t = h_t + 1572864;            // 3145728
  ushort_t* iw_t = y_t + 3145728;           // 150994944
  ushort_t* ow_t = iw_t + 150994944;        // 75497472

  k_presplit<<<2048, 256, 0, stream>>>(ipw, iw_t, 1024, 12 * 524288);
  k_presplit<<<2048, 256, 0, stream>>>(opw, ow_t, 2048, 12 * 262144);
  k_negA<<<1536, 256, 0, stream>>>(alog, negA, 12 * D_INNER * D_STATE);
  k_input_proj<<<2048, 256, 0, stream>>>(x_t, Win, bin, h_t);

  for (int l = 0; l < DEPTH; ++l) {
    const ushort_t* iw = iw_t + (size_t)l * 12582912;
    const ushort_t* ow = ow_t + (size_t)l * 6291456;
    k_gemm6<8, 32, 4, 32><<<1024, 256, 0, stream>>>(h_t, iw, Pin, 4096);
    k_fused<<<512, 256, 0, stream>>>(
        Pin,
        cst + (size_t)l * BATCH * D_INNER * D_CONV,
        sst + (size_t)l * BATCH * D_INNER * D_STATE,
        cw + (size_t)l * D_INNER * D_CONV, cb + (size_t)l * D_INNER,
        xpw + (size_t)l * 96 * D_INNER,
        dtw + (size_t)l * D_INNER * DT_RANK, dtb + (size_t)l * D_INNER,
        negA + (size_t)l * D_INNER * D_STATE, dpar + (size_t)l * D_INNER,
        y_t);
    k_gemm6<8, 8, 16, 64><<<1024, 256, 0, stream>>>(y_t, ow, Pout, 1024);
    k_reduce_out<<<512, 256, 0, stream>>>(Pout, h, h_t);
  }

  k_layernorm<<<512, 256, 0, stream>>>(h, lnw, lnb, (float*)d_out);
}

// Round 15
// 1859.004 us; speedup vs baseline: 1.1280x; 1.1280x over previous
//
#include <hip/hip_runtime.h>

#define D_IN 8
#define D_MODEL 1024
#define DEPTH 12
#define D_INNER 2048
#define D_STATE 16
#define D_CONV 4
#define DT_RANK 64
#define BATCH 512

typedef unsigned short ushort_t;
typedef unsigned int uint_t;
typedef __attribute__((ext_vector_type(8))) short short8;
typedef __attribute__((ext_vector_type(16))) float f32x16;

#if defined(__has_builtin)
#if __has_builtin(__builtin_amdgcn_global_load_lds)
#define USE_GLL 1
#endif
#endif

__device__ __forceinline__ float sigmoidf_(float x) { return 1.f / (1.f + expf(-x)); }
__device__ __forceinline__ float siluf_(float x) { return x * sigmoidf_(x); }
__device__ __forceinline__ float softplusf_(float x) { return fmaxf(x, 0.f) + log1pf(expf(-fabsf(x))); }

__device__ __forceinline__ float waveRedSum(float v) {
#pragma unroll
  for (int off = 32; off; off >>= 1) v += __shfl_xor(v, off);
  return v;
}

// ---- bf16 3-way split helpers (RNE) ----
__device__ __forceinline__ ushort_t f2bf(float x) {
  uint_t u = __float_as_uint(x);
  u += 0x7fffu + ((u >> 16) & 1u);
  return (ushort_t)(u >> 16);
}
__device__ __forceinline__ float bf2f(ushort_t h) { return __uint_as_float((uint_t)h << 16); }
__device__ __forceinline__ void split3(float x, ushort_t& s0, ushort_t& s1, ushort_t& s2) {
  s0 = f2bf(x); float r = x - bf2f(s0);
  s1 = f2bf(r); r -= bf2f(s1);
  s2 = f2bf(r);
}
__device__ __forceinline__ uint4 pack8(const ushort_t* u) {
  uint4 v;
  v.x = (uint_t)u[0] | ((uint_t)u[1] << 16);
  v.y = (uint_t)u[2] | ((uint_t)u[3] << 16);
  v.z = (uint_t)u[4] | ((uint_t)u[5] << 16);
  v.w = (uint_t)u[6] | ((uint_t)u[7] << 16);
  return v;
}

// Tile geometry: 32-ushort (64B) rows, 4x16B slots, slot' = slot ^ ((row>>1)&3).
__device__ __forceinline__ int slotx(int row, int slot) { return slot ^ ((row >> 1) & 3); }

// staging: copy 16B per lane; GLL path: lds base wave-uniform, HW adds lane*16.
__device__ __forceinline__ void stage16(const ushort_t* gbase, ushort_t* lbase, int lane) {
#ifdef USE_GLL
  __builtin_amdgcn_global_load_lds(
      (const __attribute__((address_space(1))) unsigned int*)(gbase + lane * 8),
      (__attribute__((address_space(3))) unsigned int*)lbase, 16, 0, 0);
#else
  *(uint4*)(lbase + lane * 8) = *(const uint4*)(gbase + lane * 8);
#endif
}

// ---- weight pre-split into tiled B-layout: [nb][kb][3][128 rows][32 k-ushorts] ----
__global__ __launch_bounds__(256) void k_presplit(const float* __restrict__ W,
    ushort_t* __restrict__ Bt, int K, int items) {
  const int KB = K >> 5;
  for (int i = blockIdx.x * 256 + threadIdx.x; i < items; i += gridDim.x * 256) {
    const int kpr = K >> 3;
    const int n = i / kpr, k0 = (i - n * kpr) * 8;
    const float* g = W + (size_t)n * K + k0;
    float fv[8];
    *(float4*)&fv[0] = *(const float4*)(g + 0);
    *(float4*)&fv[4] = *(const float4*)(g + 4);
    ushort_t u0[8], u1[8], u2[8];
#pragma unroll
    for (int j = 0; j < 8; ++j) split3(fv[j], u0[j], u1[j], u2[j]);
    const int nb = n >> 7, r = n & 127, kb = k0 >> 5;
    const int so = slotx(r, (k0 >> 3) & 3) * 8;
    const size_t dst = ((size_t)(nb * KB + kb) * 3) * 4096 + r * 32 + so;
    *(uint4*)&Bt[dst]        = pack8(u0);
    *(uint4*)&Bt[dst + 4096] = pack8(u1);
    *(uint4*)&Bt[dst + 8192] = pack8(u2);
  }
}

// negA = -exp(A_log), all layers (12*2048*16 floats)
__global__ __launch_bounds__(256) void k_negA(const float* __restrict__ alog,
    float* __restrict__ negA, int items) {
  int i = blockIdx.x * 256 + threadIdx.x;
  if (i < items) negA[i] = -expf(alog[i]);
}

// h[b,m] -> tiled A-layout h_t: [mb][kb(32)][3][64 rows][32]
__global__ __launch_bounds__(256) void k_input_proj(const float* __restrict__ xt,
    const float* __restrict__ Win, const float* __restrict__ bin,
    ushort_t* __restrict__ h_t) {
  int idx = blockIdx.x * 256 + threadIdx.x;
  int b = idx >> 10, m = idx & 1023;
  float acc = bin[m];
  const float* xr = xt + b * D_IN;
  const float* wr = Win + m * D_IN;
#pragma unroll
  for (int k = 0; k < D_IN; ++k) acc += xr[k] * wr[k];
  ushort_t s0, s1, s2; split3(acc, s0, s1, s2);
  const int mb = b >> 6, r = b & 63, kb = m >> 5;
  const int so = slotx(r, (m >> 3) & 3) * 8;
  const size_t base = ((size_t)(mb * 32 + kb) * 3) * 2048 + r * 32 + so + (m & 7);
  h_t[base] = s0; h_t[base + 2048] = s1; h_t[base + 4096] = s2;
}

// P_partial[kb] = A . B^T. Block 64m x 128n, BK=32, 4 waves (2 n-groups x 2 k-chunks).
template <int MBLK, int NBLK, int KSPLIT, int KB>
__global__ __launch_bounds__(256, 4) void k_gemm6(
    const ushort_t* __restrict__ At, const ushort_t* __restrict__ Bt,
    float* __restrict__ P, int N) {
  __shared__ __align__(16) ushort_t lds[18432];  // 36864 B
  const int t = threadIdx.x, lane = t & 63, w = t >> 6;
  const int wm = w >> 1;   // n-group (0,1)
  const int ks = w & 1;    // k16-chunk (0,1)

  constexpr int GRID = MBLK * NBLK * KSPLIT;
  constexpr int STEPS = KB / KSPLIT;
  const int id = blockIdx.x;
  const int swz = (id & 7) * (GRID >> 3) + (id >> 3);
  const int kb = swz / (MBLK * NBLK);
  const int r2 = swz % (MBLK * NBLK);
  const int mb = r2 % MBLK, nb = r2 / MBLK;

  f32x16 acc[2][2];
#pragma unroll
  for (int i = 0; i < 2; ++i)
#pragma unroll
    for (int j = 0; j < 2; ++j)
#pragma unroll
      for (int r = 0; r < 16; ++r) acc[i][j][r] = 0.f;

  for (int step = 0; step < STEPS; ++step) {
    const int kt = kb * STEPS + step;
    const ushort_t* gA = At + ((size_t)(mb * KB + kt)) * 6144;
    const ushort_t* gB = Bt + ((size_t)(nb * KB + kt)) * 12288;
    __syncthreads();
#pragma unroll
    for (int i = 0; i < 9; ++i) {
      const int c = w + i * 4;  // 0..35
      const ushort_t* src = (c < 12) ? (gA + c * 512) : (gB + (c - 12) * 512);
      stage16(src, &lds[c * 512], lane);
    }
    __syncthreads();

    const int kslot = ks * 2 + (lane >> 5);
    short8 af[2][3], bf[2][3];
#pragma unroll
    for (int mf = 0; mf < 2; ++mf) {
      const int r = mf * 32 + (lane & 31);
      const int so = slotx(r, kslot) * 8;
#pragma unroll
      for (int s = 0; s < 3; ++s)
        af[mf][s] = *(const short8*)&lds[s * 2048 + r * 32 + so];
    }
#pragma unroll
    for (int nf = 0; nf < 2; ++nf) {
      const int r = wm * 64 + nf * 32 + (lane & 31);
      const int so = slotx(r, kslot) * 8;
#pragma unroll
      for (int s = 0; s < 3; ++s)
        bf[nf][s] = *(const short8*)&lds[6144 + s * 4096 + r * 32 + so];
    }
#pragma unroll
    for (int mf = 0; mf < 2; ++mf)
#pragma unroll
      for (int nf = 0; nf < 2; ++nf) {
        acc[mf][nf] = __builtin_amdgcn_mfma_f32_32x32x16_bf16(af[mf][0], bf[nf][0], acc[mf][nf], 0, 0, 0);
        acc[mf][nf] = __builtin_amdgcn_mfma_f32_32x32x16_bf16(af[mf][0], bf[nf][1], acc[mf][nf], 0, 0, 0);
        acc[mf][nf] = __builtin_amdgcn_mfma_f32_32x32x16_bf16(af[mf][1], bf[nf][0], acc[mf][nf], 0, 0, 0);
        acc[mf][nf] = __builtin_amdgcn_mfma_f32_32x32x16_bf16(af[mf][1], bf[nf][1], acc[mf][nf], 0, 0, 0);
        acc[mf][nf] = __builtin_amdgcn_mfma_f32_32x32x16_bf16(af[mf][2], bf[nf][0], acc[mf][nf], 0, 0, 0);
        acc[mf][nf] = __builtin_amdgcn_mfma_f32_32x32x16_bf16(af[mf][0], bf[nf][2], acc[mf][nf], 0, 0, 0);
      }
  }

  __syncthreads();
  float* red = (float*)lds;
  const int rbase = (wm * 64 + lane) * 68;
  if (ks == 1) {
#pragma unroll
    for (int j = 0; j < 16; ++j) {
      const int mf = j >> 3, nf = (j >> 2) & 1, r0 = (j & 3) * 4;
      float4 v;
      v.x = acc[mf][nf][r0 + 0]; v.y = acc[mf][nf][r0 + 1];
      v.z = acc[mf][nf][r0 + 2]; v.w = acc[mf][nf][r0 + 3];
      *(float4*)&red[rbase + j * 4] = v;
    }
  }
  __syncthreads();
  if (ks == 0) {
#pragma unroll
    for (int j = 0; j < 16; ++j) {
      const int mf = j >> 3, nf = (j >> 2) & 1, r0 = (j & 3) * 4;
      float4 v = *(const float4*)&red[rbase + j * 4];
      acc[mf][nf][r0 + 0] += v.x; acc[mf][nf][r0 + 1] += v.y;
      acc[mf][nf][r0 + 2] += v.z; acc[mf][nf][r0 + 3] += v.w;
    }
    float* Pk = P + (size_t)kb * 512 * N;
    const int n0 = nb * 128, m0 = mb * 64;
#pragma unroll
    for (int mf = 0; mf < 2; ++mf) {
      const int n = n0 + wm * 64 + (lane & 31);
#pragma unroll
      for (int nf = 0; nf < 2; ++nf)
#pragma unroll
        for (int r = 0; r < 16; ++r) {
          const int m = m0 + mf * 32 + (r & 3) + 8 * (r >> 2) + 4 * (lane >> 5);
          Pk[(size_t)m * N + n + nf * 32] = acc[mf][nf][r];
        }
    }
  }
}

// Fused: (sum 4 Pin partials) conv+SiLU -> x_proj (vectorized) -> dt_proj+softplus
// -> SSM (vectorized sst/negA) -> gate. 1 batch row per block, 512 blocks.
__global__ __launch_bounds__(256) void k_fused(
    const float* __restrict__ Pin,   // [4][512][4096]
    const float* __restrict__ cst, const float* __restrict__ sst,
    const float* __restrict__ cw, const float* __restrict__ cb,
    const float* __restrict__ xpw, const float* __restrict__ dtw, const float* __restrict__ dtb,
    const float* __restrict__ negA, const float* __restrict__ dpar,
    ushort_t* __restrict__ y_t) {
  __shared__ float sxc[D_INNER];
  __shared__ float sxdb[96];
  const int t = threadIdx.x;
  const int b = blockIdx.x;
  const size_t S = 2097152;

  // phase 1: conv + silu
  for (int d = t; d < D_INNER; d += 256) {
    float4 c = *(const float4*)&cst[((size_t)b * D_INNER + d) * 4];
    float4 w = *(const float4*)&cw[d * 4];
    const size_t xi = (size_t)b * 4096 + d;
    float xv = Pin[xi] + Pin[xi + S] + Pin[xi + 2 * S] + Pin[xi + 3 * S];
    float a = c.y * w.x + c.z * w.y + c.w * w.z + xv * w.w + cb[d];
    sxc[d] = siluf_(a);
  }
  __syncthreads();

  // phase 2: x_proj — float4 loads, 2 rows in flight
  const int wave = t >> 6, lane = t & 63;
  const int lane4 = lane * 4;
  for (int r0 = wave * 24; r0 < wave * 24 + 24; r0 += 2) {
    const float* w0 = &xpw[(size_t)r0 * D_INNER];
    const float* w1 = w0 + D_INNER;
    float a0 = 0.f, a1 = 0.f, c0 = 0.f, c1 = 0.f;
#pragma unroll
    for (int it = 0; it < 8; ++it) {
      const int k = it * 256 + lane4;
      float4 x  = *(const float4*)&sxc[k];
      float4 wa = *(const float4*)&w0[k];
      float4 wb = *(const float4*)&w1[k];
      a0 += wa.x * x.x + wa.y * x.y;  a1 += wa.z * x.z + wa.w * x.w;
      c0 += wb.x * x.x + wb.y * x.y;  c1 += wb.z * x.z + wb.w * x.w;
    }
    float ra = waveRedSum(a0 + a1);
    float rb = waveRedSum(c0 + c1);
    if (lane == 0) { sxdb[r0] = ra; sxdb[r0 + 1] = rb; }
  }
  __syncthreads();

  // phase 3: dt_proj + softplus + SSM + gate (vectorized sst/negA)
  for (int d = t; d < D_INNER; d += 256) {
    float dtr = dtb[d];
#pragma unroll
    for (int j4 = 0; j4 < DT_RANK / 4; ++j4) {
      float4 wv = *(const float4*)&dtw[(size_t)d * DT_RANK + j4 * 4];
      dtr += sxdb[j4 * 4] * wv.x + sxdb[j4 * 4 + 1] * wv.y +
             sxdb[j4 * 4 + 2] * wv.z + sxdb[j4 * 4 + 3] * wv.w;
    }
    float dtv = softplusf_(dtr);
    float xcv = sxc[d];
    float dx = dtv * xcv;
    const float4* srow4 = (const float4*)&sst[((size_t)b * D_INNER + d) * D_STATE];
    const float4* na4 = (const float4*)&negA[(size_t)d * D_STATE];
    float acc = 0.f;
#pragma unroll
    for (int q = 0; q < 4; ++q) {
      float4 sv = srow4[q];
      float4 na = na4[q];
      float4 Bn = *(const float4*)&sxdb[DT_RANK + q * 4];
      float4 Cn = *(const float4*)&sxdb[DT_RANK + D_STATE + q * 4];
      acc += (sv.x * expf(dtv * na.x) + dx * Bn.x) * Cn.x;
      acc += (sv.y * expf(dtv * na.y) + dx * Bn.y) * Cn.y;
      acc += (sv.z * expf(dtv * na.z) + dx * Bn.z) * Cn.z;
      acc += (sv.w * expf(dtv * na.w) + dx * Bn.w) * Cn.w;
    }
    float yv = acc + dpar[d] * xcv;
    const size_t zi = (size_t)b * 4096 + D_INNER + d;
    float zv = Pin[zi] + Pin[zi + S] + Pin[zi + 2 * S] + Pin[zi + 3 * S];
    yv *= siluf_(zv);
    ushort_t s0, s1, s2; split3(yv, s0, s1, s2);
    const int mb = b >> 6, r = b & 63, kb = d >> 5;
    const int so = slotx(r, (d >> 3) & 3) * 8;
    const size_t base = ((size_t)(mb * 64 + kb) * 3) * 2048 + r * 32 + so + (d & 7);
    y_t[base] = s0; y_t[base + 2048] = s1; y_t[base + 4096] = s2;
  }
}

// h = sum of 16 out_proj partials; emit h fp32 + tiled h splits (KB=32)
__global__ __launch_bounds__(256) void k_reduce_out(const float* __restrict__ P,
    float* __restrict__ h, ushort_t* __restrict__ h_t) {
  const int i = blockIdx.x * 256 + threadIdx.x;  // 131072 float4
  float4 a = ((const float4*)P)[i];
#pragma unroll
  for (int p = 1; p < 16; ++p) {
    float4 b = ((const float4*)P)[(size_t)p * 131072 + i];
    a.x += b.x; a.y += b.y; a.z += b.z; a.w += b.w;
  }
  ((float4*)h)[i] = a;
  float fv[4] = {a.x, a.y, a.z, a.w};
  ushort_t u0[4], u1[4], u2[4];
#pragma unroll
  for (int j = 0; j < 4; ++j) split3(fv[j], u0[j], u1[j], u2[j]);
  const int flat = i * 4;
  const int b = flat >> 10, k = flat & 1023;
  const int mb = b >> 6, r = b & 63, kb = k >> 5;
  const int so = slotx(r, (k >> 3) & 3) * 8;
  const size_t base = ((size_t)(mb * 32 + kb) * 3) * 2048 + r * 32 + so + (k & 7);
  *(uint2*)&h_t[base]        = make_uint2((uint_t)u0[0] | ((uint_t)u0[1] << 16), (uint_t)u0[2] | ((uint_t)u0[3] << 16));
  *(uint2*)&h_t[base + 2048] = make_uint2((uint_t)u1[0] | ((uint_t)u1[1] << 16), (uint_t)u1[2] | ((uint_t)u1[3] << 16));
  *(uint2*)&h_t[base + 4096] = make_uint2((uint_t)u2[0] | ((uint_t)u2[1] << 16), (uint_t)u2[2] | ((uint_t)u2[3] << 16));
}

__global__ __launch_bounds__(256) void k_layernorm(const float* __restrict__ h,
    const float* __restrict__ lnw, const float* __restrict__ lnb, float* __restrict__ out) {
  __shared__ float red[4];
  const int b = blockIdx.x, t = threadIdx.x;
  const float* row = h + (size_t)b * D_MODEL;
  float4 x = *(const float4*)&row[t * 4];
  float s = x.x + x.y + x.z + x.w;
  s = waveRedSum(s);
  const int wave = t >> 6, lane = t & 63;
  if (lane == 0) red[wave] = s;
  __syncthreads();
  float mu = (red[0] + red[1] + red[2] + red[3]) * (1.f / 1024.f);
  float d0 = x.x - mu, d1 = x.y - mu, d2 = x.z - mu, d3 = x.w - mu;
  float q = d0 * d0 + d1 * d1 + d2 * d2 + d3 * d3;
  q = waveRedSum(q);
  __syncthreads();
  if (lane == 0) red[wave] = q;
  __syncthreads();
  float var = (red[0] + red[1] + red[2] + red[3]) * (1.f / 1024.f);
  float inv = 1.f / sqrtf(var + 1e-5f);
  float4 wv = *(const float4*)&lnw[t * 4];
  float4 bv = *(const float4*)&lnb[t * 4];
  float4 o;
  o.x = d0 * inv * wv.x + bv.x;
  o.y = d1 * inv * wv.y + bv.y;
  o.z = d2 * inv * wv.z + bv.z;
  o.w = d3 * inv * wv.w + bv.w;
  *(float4*)&out[(size_t)b * D_MODEL + t * 4] = o;
}

extern "C" void kernel_launch(void* const* d_in, const int* in_sizes, int n_in,
                              void* d_out, int out_size, void* d_ws, size_t ws_size,
                              hipStream_t stream) {
  const float* x_t  = (const float*)d_in[0];
  const float* cst  = (const float*)d_in[1];
  const float* sst  = (const float*)d_in[2];
  const float* Win  = (const float*)d_in[3];
  const float* bin  = (const float*)d_in[4];
  const float* ipw  = (const float*)d_in[5];
  const float* cw   = (const float*)d_in[6];
  const float* cb   = (const float*)d_in[7];
  const float* xpw  = (const float*)d_in[8];
  const float* dtw  = (const float*)d_in[9];
  const float* dtb  = (const float*)d_in[10];
  const float* alog = (const float*)d_in[11];
  const float* dpar = (const float*)d_in[12];
  const float* opw  = (const float*)d_in[13];
  const float* lnw  = (const float*)d_in[14];
  const float* lnb  = (const float*)d_in[15];

  float* ws   = (float*)d_ws;
  float* h    = ws;                         // 524288 f32
  float* Pin  = h + 524288;                 // 4 x 2097152 f32
  float* Pout = Pin + 8388608;              // 16 x 524288 f32
  float* negA = Pout + 8388608;             // 393216 f32
  ushort_t* u = (ushort_t*)(negA + 393216);
  ushort_t* h_t = u;                        // 1572864
  ushort_t* y_t = h_t + 1572864;            // 3145728
  ushort_t* iw_t = y_t + 3145728;           // 150994944
  ushort_t* ow_t = iw_t + 150994944;        // 75497472

  k_presplit<<<2048, 256, 0, stream>>>(ipw, iw_t, 1024, 12 * 524288);
  k_presplit<<<2048, 256, 0, stream>>>(opw, ow_t, 2048, 12 * 262144);
  k_negA<<<1536, 256, 0, stream>>>(alog, negA, 12 * D_INNER * D_STATE);
  k_input_proj<<<2048, 256, 0, stream>>>(x_t, Win, bin, h_t);

  for (int l = 0; l < DEPTH; ++l) {
    const ushort_t* iw = iw_t + (size_t)l * 12582912;
    const ushort_t* ow = ow_t + (size_t)l * 6291456;
    k_gemm6<8, 32, 4, 32><<<1024, 256, 0, stream>>>(h_t, iw, Pin, 4096);
    k_fused<<<512, 256, 0, stream>>>(
        Pin,
        cst + (size_t)l * BATCH * D_INNER * D_CONV,
        sst + (size_t)l * BATCH * D_INNER * D_STATE,
        cw + (size_t)l * D_INNER * D_CONV, cb + (size_t)l * D_INNER,
        xpw + (size_t)l * 96 * D_INNER,
        dtw + (size_t)l * D_INNER * DT_RANK, dtb + (size_t)l * D_INNER,
        negA + (size_t)l * D_INNER * D_STATE, dpar + (size_t)l * D_INNER,
        y_t);
    k_gemm6<8, 8, 16, 64><<<1024, 256, 0, stream>>>(y_t, ow, Pout, 1024);
    k_reduce_out<<<512, 256, 0, stream>>>(Pout, h, h_t);
  }

  k_layernorm<<<512, 256, 0, stream>>>(h, lnw, lnb, (float*)d_out);
}